// Round 5
// baseline (90.004 us; speedup 1.0000x reference)
//
#include <hip/hip_runtime.h>
#include <math.h>

// Problem constants (fixed by reference setup_inputs / module constants)
#define BB   8      // batch
#define NP   4096   // proposals per image
#define NG   512    // gt boxes per image
#define TT   200    // TRAIN_ROIS
#define PMAX 66     // int(200 * 0.33)

#define CH   8      // gt chunks per block
#define PB   32     // proposals per block (256 threads / CH)
#define NBLK (NP / PB)   // 128 proposal-blocks per image

// ---------------------------------------------------------------------------
// Fused single kernel. Grid: BB*128 blocks of 256 threads.
//
// Phase A (all blocks): per proposal, max IoU over gt boxes + first-argmax
// (jnp.argmax tie-break). 4-wave parallel stable compaction of valid gts into
// LDS (ascending original j; invalid columns can never win: iou >= 0 > -1).
// 256 threads = 32 proposals x 8 ordered chunks over compacted gts; argmax
// tracked in compacted index (ascending j -> first-max preserved), mapped
// back via one sidx read. Per-iter LDS = one ds_read_b128 (a2 recomputed in
// registers, reference expr/order -> bit-identical). Emits per-block 32-bit
// pos/neg ballot masks + argj to global.
//
// Ticket (rocPRIM last-block pattern): __syncthreads() drains this block's
// stores into its XCD L2; thread 0 __threadfence() (agent release:
// buffer_wbl2 flushes L2 to the common point) + device-scope atomicAdd on
// counters[b]. d_ws is poisoned 0xAA each launch, so the ticket starts at
// 0xAAAAAAAA; the 128th arriver sees old == 0xAAAAAAAA+127 (or 127 if the
// buffer were zeroed). That unique block acquires (__threadfence ->
// buffer_inv) and runs Phase B for image b.
//
// Phase B (last block per image): wave 0 scans the 128 pos masks, wave 1 the
// neg masks (wave-synchronous shfl_up prefix scan), bit-emits ordered index
// lists (PMAX/TT caps lossless), then each thread owns one output slot
// exclusively -> every output element written exactly once per launch.
// ---------------------------------------------------------------------------
__global__ __launch_bounds__(256) void fused_phase(
    const float* __restrict__ proposals, const float* __restrict__ gt,
    const int* __restrict__ caps, const float* __restrict__ scores,
    int* __restrict__ argj, unsigned int* __restrict__ posmask,
    unsigned int* __restrict__ negmask, unsigned int* __restrict__ counters,
    float* __restrict__ out) {
#pragma clang fp contract(off)
  const int b     = blockIdx.x >> 7;          // / 128
  const int blk   = blockIdx.x & 127;
  const int pbase = blk * PB;

  __shared__ float4 sgt[NG];    // compacted valid gt boxes (ascending j)
  __shared__ short  sidx[NG];   // their original j
  __shared__ int    s_wcnt[4];
  __shared__ float  rbest[CH][PB];
  __shared__ int    ridx[CH][PB];
  __shared__ unsigned int s_old;
  __shared__ int    s_pos[PMAX];
  __shared__ int    s_neg[TT];
  __shared__ int    s_tot[2];

  const int tid  = threadIdx.x;
  const int wave = tid >> 6;
  const int lane = tid & 63;

  const int plocal  = tid & (PB - 1);
  const int chunkid = tid >> 5;              // tid / 32
  const int i       = pbase + plocal;

  // Issue the proposal load early so it overlaps gt staging.
  const float4 p = ((const float4*)proposals)[(size_t)b * NP + i];

  // 4-wave parallel stable compaction: wave w covers gts [128w, 128w+128).
  const float4* gtb4 = (const float4*)(gt + (size_t)b * NG * 4);
  const int ja = wave * 128 + lane;
  const int jb = ja + 64;
  const float4 ga = gtb4[ja];
  const float4 gb = gtb4[jb];
  const bool va = (fabsf(ga.x) + fabsf(ga.y) + fabsf(ga.z) + fabsf(ga.w)) > 0.0f;
  const bool vb = (fabsf(gb.x) + fabsf(gb.y) + fabsf(gb.z) + fabsf(gb.w)) > 0.0f;
  const unsigned long long ma = __ballot(va);
  const unsigned long long mb = __ballot(vb);
  if (lane == 0) s_wcnt[wave] = __popcll(ma) + __popcll(mb);
  __syncthreads();

  int wbase = 0;
  for (int w = 0; w < 4; ++w) if (w < wave) wbase += s_wcnt[w];
  const int nv = s_wcnt[0] + s_wcnt[1] + s_wcnt[2] + s_wcnt[3];

  const unsigned long long lower = (1ull << lane) - 1ull;
  if (va) {
    int k = wbase + __popcll(ma & lower);
    sgt[k] = ga; sidx[k] = (short)ja;
  }
  if (vb) {
    int k = wbase + __popcll(ma) + __popcll(mb & lower);
    sgt[k] = gb; sidx[k] = (short)jb;
  }
  __syncthreads();

  const float a1  = (p.z - p.x) * (p.w - p.y);
  const int   csz = (nv + CH - 1) / CH;
  int j0 = chunkid * csz;
  int j1 = j0 + csz; if (j1 > nv) j1 = nv;
  if (j0 > nv) j0 = nv;

  float best = -INFINITY;
  int bk = 0;                                 // compacted winner index
#pragma unroll 4
  for (int j = j0; j < j1; ++j) {
    float4 g = sgt[j];                        // 32-lane broadcast (conflict-free)
    // exact reference op order (fp contract off => IEEE, matches numpy/JAX f32)
    float y1 = fmaxf(p.x, g.x);
    float x1 = fmaxf(p.y, g.y);
    float y2 = fminf(p.z, g.z);
    float x2 = fminf(p.w, g.w);
    float inter = fmaxf(x2 - x1, 0.0f) * fmaxf(y2 - y1, 0.0f);
    float a2 = (g.z - g.x) * (g.w - g.y);     // reference a2 expr/order
    float un = a1 + a2 - inter;               // (a1 + a2) - inter
    float iou = inter / (un > 0.0f ? un : 1.0f);
    if (iou > best) { best = iou; bk = j; }   // strict > = first-max (asc j)
  }
  rbest[chunkid][plocal] = best;
  ridx[chunkid][plocal]  = bk;
  __syncthreads();

  // Lanes 0..31 of wave 0 combine the 8 chunk partials in chunk order
  // (chunks cover ascending compacted j -> first-max preserved).
  if (tid < PB) {
    float bb = rbest[0][tid];
    int   bi = ridx[0][tid];
    for (int c = 1; c < CH; ++c) {
      float v = rbest[c][tid];
      if (v > bb) { bb = v; bi = ridx[c][tid]; }
    }
    int borig = (int)sidx[bi];                // compacted -> original j (1 read)
    bool vp  = (fabsf(p.x) + fabsf(p.y) + fabsf(p.z) + fabsf(p.w)) > 0.0f;
    bool isp = vp && (bb >= 0.5f);
    bool isn = vp && (bb <  0.5f);
    unsigned long long mp = __ballot(isp);    // lanes 32..63 inactive -> 0 bits
    unsigned long long mn = __ballot(isn);
    argj[(size_t)b * NP + i] = borig;
    if (tid == 0) {
      posmask[(size_t)b * NBLK + blk] = (unsigned int)mp;
      negmask[(size_t)b * NBLK + blk] = (unsigned int)mn;
    }
  }

  // ---- ticket: am I the last block of image b? ----
  __syncthreads();                 // drain all this block's stores to our L2
  if (tid == 0) {
    __threadfence();               // agent release: flush our L2 to common point
    s_old = atomicAdd(&counters[b], 1u);   // device-scope RMW
  }
  __syncthreads();
  const unsigned int old = s_old;
  const bool last = (old == 0xAAAAAAAAu + 127u) || (old == 127u);
  if (!last) return;
  __threadfence();                 // acquire: invalidate stale L2 lines

  // ---- Phase B: select for image b ----
  if (wave < 2) {
    const unsigned int* msk = (wave == 0 ? posmask : negmask) + (size_t)b * NBLK;
    const int cap = (wave == 0) ? PMAX : TT;
    int* list = (wave == 0) ? s_pos : s_neg;
    // lane l covers masks 2l, 2l+1 == proposals [64l, 64l+64)
    unsigned int m0 = msk[2 * lane];
    unsigned int m1 = msk[2 * lane + 1];
    int cnt = __popc(m0) + __popc(m1);
    int incl = cnt;
    for (int d = 1; d < 64; d <<= 1) {
      int u = __shfl_up(incl, d, 64);
      if (lane >= d) incl += u;
    }
    int base = incl - cnt;
    if (lane == 63) s_tot[wave] = incl;
    while (m0 && base < cap) {
      int bit = __ffs(m0) - 1;
      list[base] = lane * 64 + bit;
      m0 &= m0 - 1; ++base;
    }
    while (m1 && base < cap) {
      int bit = __ffs(m1) - 1;
      list[base] = lane * 64 + 32 + bit;
      m1 &= m1 - 1; ++base;
    }
  }
  __syncthreads();

  const int pos_total = s_tot[0];
  const int neg_total = s_tot[1];
  int pos_cnt = pos_total < PMAX ? pos_total : PMAX;
  // f32 semantics (JAX x64-off): 0.33f > 0.33, e.g. 66/0.33f -> 199 (trunc)
  int neg_cnt = (int)((float)pos_cnt / 0.33f) - pos_cnt;
  if (neg_total < neg_cnt)    neg_cnt = neg_total;
  if (TT - pos_cnt < neg_cnt) neg_cnt = TT - pos_cnt;
  if (neg_cnt < 0)            neg_cnt = 0;

  // Output slices (flat concat in return order: rois, deltas, caps, scores)
  float* rois   = out + (size_t)b * TT * 4;
  float* deltas = out + (size_t)BB * TT * 4 + (size_t)b * TT * 4;
  float* ocaps  = out + (size_t)2 * BB * TT * 4 + (size_t)b * TT * 15;
  float* osc    = out + (size_t)2 * BB * TT * 4 + (size_t)BB * TT * 15 + (size_t)b * TT;

  const int k = tid;
  if (k < TT) {
    if (k < pos_cnt) {
      int i2 = s_pos[k];
      const float* pp = proposals + ((size_t)b * NP + i2) * 4;
      float p0 = pp[0], p1 = pp[1], p2 = pp[2], p3 = pp[3];
      int g = argj[(size_t)b * NP + i2];
      const float* gg = gt + ((size_t)b * NG + g) * 4;
      float g0 = gg[0], g1 = gg[1], g2 = gg[2], g3 = gg[3];

      rois[k * 4 + 0] = p0; rois[k * 4 + 1] = p1;
      rois[k * 4 + 2] = p2; rois[k * 4 + 3] = p3;

      float h  = p2 - p0, ww = p3 - p1;
      float cy = p0 + 0.5f * h, cx = p1 + 0.5f * ww;
      float gh = g2 - g0, gw = g3 - g1;
      float gcy = g0 + 0.5f * gh, gcx = g1 + 0.5f * gw;
      deltas[k * 4 + 0] = ((gcy - cy) / h) / 0.1f;
      deltas[k * 4 + 1] = ((gcx - cx) / ww) / 0.1f;
      deltas[k * 4 + 2] = logf(gh / h) / 0.2f;
      deltas[k * 4 + 3] = logf(gw / ww) / 0.2f;

      const int* cp = caps + ((size_t)b * NG + g) * 15;
      for (int c = 0; c < 15; ++c) ocaps[k * 15 + c] = (float)cp[c];
      osc[k] = scores[(size_t)b * NG + g];
    } else {
      if (k < pos_cnt + neg_cnt) {
        int i2 = s_neg[k - pos_cnt];
        const float* pp = proposals + ((size_t)b * NP + i2) * 4;
        rois[k * 4 + 0] = pp[0]; rois[k * 4 + 1] = pp[1];
        rois[k * 4 + 2] = pp[2]; rois[k * 4 + 3] = pp[3];
      } else {
        rois[k * 4 + 0] = 0.0f; rois[k * 4 + 1] = 0.0f;
        rois[k * 4 + 2] = 0.0f; rois[k * 4 + 3] = 0.0f;
      }
      deltas[k * 4 + 0] = 0.0f; deltas[k * 4 + 1] = 0.0f;
      deltas[k * 4 + 2] = 0.0f; deltas[k * 4 + 3] = 0.0f;
      for (int c = 0; c < 15; ++c) ocaps[k * 15 + c] = 0.0f;
      osc[k] = 0.0f;
    }
  }
}

extern "C" void kernel_launch(void* const* d_in, const int* in_sizes, int n_in,
                              void* d_out, int out_size, void* d_ws, size_t ws_size,
                              hipStream_t stream) {
  const float* proposals = (const float*)d_in[0];  // (8,4096,4) f32
  const float* gt        = (const float*)d_in[1];  // (8,512,4)  f32
  const int*   caps      = (const int*)d_in[2];    // (8,512,15) i32
  const float* scores    = (const float*)d_in[3];  // (8,512)    f32
  float* out = (float*)d_out;                      // 38400 f32 (flat tuple)

  char* ws = (char*)d_ws;
  int*          argj = (int*)ws;                                   // 8*4096 i32
  unsigned int* pm   = (unsigned int*)(ws + (size_t)BB * NP * 4);  // 8*128 u32
  unsigned int* nm   = pm + (size_t)BB * NBLK;                     // 8*128 u32
  unsigned int* cnts = nm + (size_t)BB * NBLK;                     // 8 u32 (poisoned 0xAA base)

  hipLaunchKernelGGL(fused_phase, dim3(BB * NBLK), dim3(256), 0, stream,
                     proposals, gt, caps, scores, argj, pm, nm, cnts, out);
}

// Round 6
// 79.637 us; speedup vs baseline: 1.1302x; 1.1302x over previous
//
#include <hip/hip_runtime.h>
#include <math.h>

// Problem constants (fixed by reference setup_inputs / module constants)
#define BB   8      // batch
#define NP   4096   // proposals per image
#define NG   512    // gt boxes per image
#define TT   200    // TRAIN_ROIS
#define PMAX 66     // int(200 * 0.33)

#define CH   8      // gt chunks per block
#define NB64 (NP / 64)   // 64 proposal-blocks per image (64 proposals each)

// ---------------------------------------------------------------------------
// Phase A: per proposal, max IoU over gt boxes and first-argmax (jnp.argmax
// tie-break). 4-wave parallel stable compaction of valid gts into LDS
// (ascending original j; invalid columns can never win: iou >= 0 > -1).
// 256 threads = 32 lanes x 8 ordered chunks, TWO proposals per thread
// (p = pbase+plocal, q = p+32): each ds_read_b128 of a gt feeds two IoUs,
// halving LDS-pipe traffic vs 1 proposal/thread. Argmax tracked in compacted
// index (ascending j -> strict-> = first-max preserved), mapped back via one
// sidx read. Wave-uniform skip of the whole sweep when all 64 proposals are
// invalid (every wave holds the same 64 proposals -> identical ballot).
// Lanes 0..63 of wave 0 hold the block's proposals in ascending order
// (p for lane<32, q for lane>=32) -> pos/neg masks are ONE 64-bit ballot.
// Grid: BB * 64 = 512 blocks.
// ---------------------------------------------------------------------------
__global__ __launch_bounds__(256) void iou_phase(
    const float* __restrict__ proposals, const float* __restrict__ gt,
    int* __restrict__ argj, unsigned long long* __restrict__ posmask,
    unsigned long long* __restrict__ negmask) {
#pragma clang fp contract(off)
  const int b     = blockIdx.x >> 6;          // / 64
  const int blk   = blockIdx.x & 63;
  const int pbase = blk * 64;

  __shared__ float4 sgt[NG];    // compacted valid gt boxes (ascending j)
  __shared__ short  sidx[NG];   // their original j
  __shared__ int    s_wcnt[4];
  __shared__ float  rbest[CH][64];
  __shared__ int    ridx[CH][64];

  const int tid  = threadIdx.x;
  const int wave = tid >> 6;
  const int lane = tid & 63;

  const int plocal  = tid & 31;
  const int chunkid = tid >> 5;              // tid / 32
  const int ip      = pbase + plocal;
  const int iq      = ip + 32;

  // Issue both proposal loads early so they overlap gt staging.
  const float4 p = ((const float4*)proposals)[(size_t)b * NP + ip];
  const float4 q = ((const float4*)proposals)[(size_t)b * NP + iq];

  // 4-wave parallel stable compaction: wave w covers gts [128w, 128w+128).
  const float4* gtb4 = (const float4*)(gt + (size_t)b * NG * 4);
  const int ja = wave * 128 + lane;
  const int jb = ja + 64;
  const float4 ga = gtb4[ja];
  const float4 gb = gtb4[jb];
  const bool va = (fabsf(ga.x) + fabsf(ga.y) + fabsf(ga.z) + fabsf(ga.w)) > 0.0f;
  const bool vb = (fabsf(gb.x) + fabsf(gb.y) + fabsf(gb.z) + fabsf(gb.w)) > 0.0f;
  const unsigned long long ma = __ballot(va);
  const unsigned long long mb = __ballot(vb);
  if (lane == 0) s_wcnt[wave] = __popcll(ma) + __popcll(mb);
  __syncthreads();

  int wbase = 0;
  for (int w = 0; w < 4; ++w) if (w < wave) wbase += s_wcnt[w];
  const int nv = s_wcnt[0] + s_wcnt[1] + s_wcnt[2] + s_wcnt[3];

  const unsigned long long lower = (1ull << lane) - 1ull;
  if (va) {
    int k = wbase + __popcll(ma & lower);
    sgt[k] = ga; sidx[k] = (short)ja;
  }
  if (vb) {
    int k = wbase + __popcll(ma) + __popcll(mb & lower);
    sgt[k] = gb; sidx[k] = (short)jb;
  }
  __syncthreads();

  const float a1p = (p.z - p.x) * (p.w - p.y);
  const float a1q = (q.z - q.x) * (q.w - q.y);
  const int   csz = (nv + CH - 1) / CH;
  int j0 = chunkid * csz;
  int j1 = j0 + csz; if (j1 > nv) j1 = nv;
  if (j0 > nv) j0 = nv;

  const bool vpp = (fabsf(p.x) + fabsf(p.y) + fabsf(p.z) + fabsf(p.w)) > 0.0f;
  const bool vpq = (fabsf(q.x) + fabsf(q.y) + fabsf(q.z) + fabsf(q.w)) > 0.0f;
  // Wave-uniform: every wave holds the same 64 proposals of this block.
  const bool any_valid = __ballot(vpp || vpq) != 0ull;

  float bestp = -INFINITY, bestq = -INFINITY;
  int bkp = 0, bkq = 0;                       // compacted winner indices
  if (any_valid) {
#pragma unroll 2
    for (int j = j0; j < j1; ++j) {
      float4 g = sgt[j];                      // 32-lane broadcast (conflict-free)
      float a2 = (g.z - g.x) * (g.w - g.y);   // reference a2 expr/order
      // exact reference op order (fp contract off => IEEE, matches JAX f32)
      {
        float y1 = fmaxf(p.x, g.x);
        float x1 = fmaxf(p.y, g.y);
        float y2 = fminf(p.z, g.z);
        float x2 = fminf(p.w, g.w);
        float inter = fmaxf(x2 - x1, 0.0f) * fmaxf(y2 - y1, 0.0f);
        float un = a1p + a2 - inter;          // (a1 + a2) - inter
        float iou = inter / (un > 0.0f ? un : 1.0f);
        if (iou > bestp) { bestp = iou; bkp = j; }  // strict > = first-max
      }
      {
        float y1 = fmaxf(q.x, g.x);
        float x1 = fmaxf(q.y, g.y);
        float y2 = fminf(q.z, g.z);
        float x2 = fminf(q.w, g.w);
        float inter = fmaxf(x2 - x1, 0.0f) * fmaxf(y2 - y1, 0.0f);
        float un = a1q + a2 - inter;
        float iou = inter / (un > 0.0f ? un : 1.0f);
        if (iou > bestq) { bestq = iou; bkq = j; }
      }
    }
  }
  rbest[chunkid][plocal]      = bestp;
  ridx[chunkid][plocal]       = bkp;
  rbest[chunkid][plocal + 32] = bestq;
  ridx[chunkid][plocal + 32]  = bkq;
  __syncthreads();

  // Wave 0 (lanes 0..63) combines the 8 chunk partials in chunk order
  // (chunks cover ascending compacted j -> first-max preserved).
  if (tid < 64) {
    float bb = rbest[0][tid];
    int   bi = ridx[0][tid];
    for (int c = 1; c < CH; ++c) {
      float v = rbest[c][tid];
      if (v > bb) { bb = v; bi = ridx[c][tid]; }
    }
    int borig = (int)sidx[bi];                // compacted -> original j (1 read)
    // Lane tid holds proposal pbase+tid: p if tid<32, else its q.
    const float4 mine = (tid < 32) ? p : q;
    bool vp  = (fabsf(mine.x) + fabsf(mine.y) + fabsf(mine.z) + fabsf(mine.w)) > 0.0f;
    bool isp = vp && (bb >= 0.5f);
    bool isn = vp && (bb <  0.5f);
    unsigned long long mp = __ballot(isp);    // bit l = proposal pbase+l
    unsigned long long mn = __ballot(isn);
    argj[(size_t)b * NP + pbase + tid] = borig;
    if (tid == 0) {
      posmask[(size_t)b * NB64 + blk] = mp;
      negmask[(size_t)b * NB64 + blk] = mn;
    }
  }
}

// ---------------------------------------------------------------------------
// Phase B: per image (1 block). Wave 0 scans the 64 pos masks, wave 1 the
// 64 neg masks (one 64-bit mask per lane, wave-synchronous shfl_up prefix
// scan, no barriers), bit-emitting ordered index lists (PMAX/TT caps are
// lossless). One barrier, then each thread owns one output slot exclusively
// and writes every output element exactly once (d_out re-poisoned per launch).
// ---------------------------------------------------------------------------
__global__ __launch_bounds__(256) void select_phase(
    const float* __restrict__ proposals, const float* __restrict__ gt,
    const int* __restrict__ caps, const float* __restrict__ scores,
    const int* __restrict__ argj, const unsigned long long* __restrict__ posmask,
    const unsigned long long* __restrict__ negmask, float* __restrict__ out) {
#pragma clang fp contract(off)
  const int b = blockIdx.x;

  __shared__ int s_pos[PMAX];
  __shared__ int s_neg[TT];
  __shared__ int s_tot[2];

  const int tid  = threadIdx.x;
  const int wave = tid >> 6;
  const int lane = tid & 63;

  if (wave < 2) {
    const unsigned long long* msk =
        (wave == 0 ? posmask : negmask) + (size_t)b * NB64;
    const int cap = (wave == 0) ? PMAX : TT;
    int* list = (wave == 0) ? s_pos : s_neg;
    unsigned long long m = msk[lane];         // proposals [64*lane, 64*lane+64)
    int cnt = __popcll(m);
    int incl = cnt;
    for (int d = 1; d < 64; d <<= 1) {
      int u = __shfl_up(incl, d, 64);
      if (lane >= d) incl += u;
    }
    int base = incl - cnt;
    if (lane == 63) s_tot[wave] = incl;
    while (m && base < cap) {
      int bit = __ffsll((unsigned long long)m) - 1;
      list[base] = lane * 64 + bit;
      m &= m - 1; ++base;
    }
  }
  __syncthreads();

  const int pos_total = s_tot[0];
  const int neg_total = s_tot[1];
  int pos_cnt = pos_total < PMAX ? pos_total : PMAX;
  // f32 semantics (JAX x64-off): 0.33f > 0.33, e.g. 66/0.33f -> 199 (trunc)
  int neg_cnt = (int)((float)pos_cnt / 0.33f) - pos_cnt;
  if (neg_total < neg_cnt)    neg_cnt = neg_total;
  if (TT - pos_cnt < neg_cnt) neg_cnt = TT - pos_cnt;
  if (neg_cnt < 0)            neg_cnt = 0;

  // Output slices (flat concat in return order: rois, deltas, caps, scores)
  float* rois   = out + (size_t)b * TT * 4;
  float* deltas = out + (size_t)BB * TT * 4 + (size_t)b * TT * 4;
  float* ocaps  = out + (size_t)2 * BB * TT * 4 + (size_t)b * TT * 15;
  float* osc    = out + (size_t)2 * BB * TT * 4 + (size_t)BB * TT * 15 + (size_t)b * TT;

  const int k = tid;
  if (k < TT) {
    if (k < pos_cnt) {
      int i = s_pos[k];
      const float* pp = proposals + ((size_t)b * NP + i) * 4;
      float p0 = pp[0], p1 = pp[1], p2 = pp[2], p3 = pp[3];
      int g = argj[(size_t)b * NP + i];
      const float* gg = gt + ((size_t)b * NG + g) * 4;
      float g0 = gg[0], g1 = gg[1], g2 = gg[2], g3 = gg[3];

      rois[k * 4 + 0] = p0; rois[k * 4 + 1] = p1;
      rois[k * 4 + 2] = p2; rois[k * 4 + 3] = p3;

      float h  = p2 - p0, ww = p3 - p1;
      float cy = p0 + 0.5f * h, cx = p1 + 0.5f * ww;
      float gh = g2 - g0, gw = g3 - g1;
      float gcy = g0 + 0.5f * gh, gcx = g1 + 0.5f * gw;
      deltas[k * 4 + 0] = ((gcy - cy) / h) / 0.1f;
      deltas[k * 4 + 1] = ((gcx - cx) / ww) / 0.1f;
      deltas[k * 4 + 2] = logf(gh / h) / 0.2f;
      deltas[k * 4 + 3] = logf(gw / ww) / 0.2f;

      const int* cp = caps + ((size_t)b * NG + g) * 15;
      for (int c = 0; c < 15; ++c) ocaps[k * 15 + c] = (float)cp[c];
      osc[k] = scores[(size_t)b * NG + g];
    } else {
      if (k < pos_cnt + neg_cnt) {
        int i = s_neg[k - pos_cnt];
        const float* pp = proposals + ((size_t)b * NP + i) * 4;
        rois[k * 4 + 0] = pp[0]; rois[k * 4 + 1] = pp[1];
        rois[k * 4 + 2] = pp[2]; rois[k * 4 + 3] = pp[3];
      } else {
        rois[k * 4 + 0] = 0.0f; rois[k * 4 + 1] = 0.0f;
        rois[k * 4 + 2] = 0.0f; rois[k * 4 + 3] = 0.0f;
      }
      deltas[k * 4 + 0] = 0.0f; deltas[k * 4 + 1] = 0.0f;
      deltas[k * 4 + 2] = 0.0f; deltas[k * 4 + 3] = 0.0f;
      for (int c = 0; c < 15; ++c) ocaps[k * 15 + c] = 0.0f;
      osc[k] = 0.0f;
    }
  }
}

extern "C" void kernel_launch(void* const* d_in, const int* in_sizes, int n_in,
                              void* d_out, int out_size, void* d_ws, size_t ws_size,
                              hipStream_t stream) {
  const float* proposals = (const float*)d_in[0];  // (8,4096,4) f32
  const float* gt        = (const float*)d_in[1];  // (8,512,4)  f32
  const int*   caps      = (const int*)d_in[2];    // (8,512,15) i32
  const float* scores    = (const float*)d_in[3];  // (8,512)    f32
  float* out = (float*)d_out;                      // 38400 f32 (flat tuple)

  char* ws = (char*)d_ws;
  int*                argj = (int*)ws;                                  // 8*4096 i32
  unsigned long long* pm   = (unsigned long long*)(ws + (size_t)BB * NP * 4); // 8*64 u64
  unsigned long long* nm   = pm + (size_t)BB * NB64;                    // 8*64 u64

  hipLaunchKernelGGL(iou_phase, dim3(BB * NB64), dim3(256), 0, stream,
                     proposals, gt, argj, pm, nm);
  hipLaunchKernelGGL(select_phase, dim3(BB), dim3(256), 0, stream,
                     proposals, gt, caps, scores, argj, pm, nm, out);
}